// Round 5
// baseline (155.604 us; speedup 1.0000x reference)
//
#include <hip/hip_runtime.h>

// reference: out[i] = dot(sort(x[i,0:3]), W[0,0:3]) + b[0]
// B = 8388608 rows, x fp32 [B,3], W fp32 [1,3], b fp32 [1], out fp32 [B,1].
// Memory-bound: 16 B/row traffic -> ~134 MB total, roofline ~21 us @ 6.3 TB/s.

__device__ __forceinline__ float sort3_dot(float a, float b, float c,
                                           float w0, float w1, float w2, float bb) {
    float mn = fminf(fminf(a, b), c);
    float mx = fmaxf(fmaxf(a, b), c);
    // exact median-of-3: max(min(a,b), min(max(a,b), c))
    float md = fmaxf(fminf(a, b), fminf(fmaxf(a, b), c));
    return fmaf(mn, w0, fmaf(md, w1, fmaf(mx, w2, bb)));
}

__global__ __launch_bounds__(256) void sort3_linear_kernel(
    const float* __restrict__ x,
    const float* __restrict__ W,
    const float* __restrict__ bias,
    float* __restrict__ out,
    int nquad)  // number of 4-row groups
{
    int i = blockIdx.x * blockDim.x + threadIdx.x;
    if (i >= nquad) return;

    // broadcast scalars (same address all lanes -> scalar loads / L2 hits)
    const float w0 = W[0], w1 = W[1], w2 = W[2];
    const float bb = bias[0];

    // 4 rows = 12 floats = 3x float4, dense across the wave
    const float4* xp = reinterpret_cast<const float4*>(x);
    float4 A  = xp[i * 3 + 0];
    float4 Bv = xp[i * 3 + 1];
    float4 C  = xp[i * 3 + 2];

    float4 o;
    o.x = sort3_dot(A.x,  A.y,  A.z,  w0, w1, w2, bb);
    o.y = sort3_dot(A.w,  Bv.x, Bv.y, w0, w1, w2, bb);
    o.z = sort3_dot(Bv.z, Bv.w, C.x,  w0, w1, w2, bb);
    o.w = sort3_dot(C.y,  C.z,  C.w,  w0, w1, w2, bb);

    reinterpret_cast<float4*>(out)[i] = o;
}

extern "C" void kernel_launch(void* const* d_in, const int* in_sizes, int n_in,
                              void* d_out, int out_size, void* d_ws, size_t ws_size,
                              hipStream_t stream) {
    const float* x  = (const float*)d_in[0];
    const float* W  = (const float*)d_in[1];
    const float* bv = (const float*)d_in[2];
    float* out = (float*)d_out;

    const int nrows = out_size;          // 8388608
    const int nquad = nrows / 4;         // 2097152 (B = 2^23, divides exactly)
    const int block = 256;
    const int grid  = (nquad + block - 1) / block;  // 8192

    sort3_linear_kernel<<<grid, block, 0, stream>>>(x, W, bv, out, nquad);
}

// Round 6
// 153.744 us; speedup vs baseline: 1.0121x; 1.0121x over previous
//
#include <hip/hip_runtime.h>

// reference: out[i] = dot(sort(x[i,0:3]), W[0,0:3]) + b[0]
// B = 8388608 rows, x fp32 [B,3], W fp32 [1,3], b fp32 [1], out fp32 [B,1].
// Memory-bound: 16 B/row traffic -> ~134 MB total, roofline ~21 us @ 6.3 TB/s.
//
// Round 6: one row per thread via float3 (12 B) load -> lane-contiguous
// (wave = one dense 768 B span per load instr, 12 granules vs 48 for the
// old stride-48 float4 pattern). Store = scalar f32, dense 256 B/wave.

__device__ __forceinline__ float sort3_dot(float a, float b, float c,
                                           float w0, float w1, float w2, float bb) {
    float mn = fminf(fminf(a, b), c);
    float mx = fmaxf(fmaxf(a, b), c);
    // exact median-of-3: max(min(a,b), min(max(a,b), c))
    float md = fmaxf(fminf(a, b), fminf(fmaxf(a, b), c));
    return fmaf(mn, w0, fmaf(md, w1, fmaf(mx, w2, bb)));
}

__global__ __launch_bounds__(256) void sort3_linear_kernel(
    const float* __restrict__ x,
    const float* __restrict__ W,
    const float* __restrict__ bias,
    float* __restrict__ out,
    int nrows)
{
    int i = blockIdx.x * blockDim.x + threadIdx.x;
    if (i >= nrows) return;

    // broadcast scalars (same address all lanes -> scalar loads / L2 hits)
    const float w0 = W[0], w1 = W[1], w2 = W[2];
    const float bb = bias[0];

    // 12 B lane-contiguous load (global_load_dwordx3): wave covers one
    // dense 768 B span, every 64 B granule fully consumed by the instr.
    float3 r = reinterpret_cast<const float3*>(x)[i];

    out[i] = sort3_dot(r.x, r.y, r.z, w0, w1, w2, bb);
}

extern "C" void kernel_launch(void* const* d_in, const int* in_sizes, int n_in,
                              void* d_out, int out_size, void* d_ws, size_t ws_size,
                              hipStream_t stream) {
    const float* x  = (const float*)d_in[0];
    const float* W  = (const float*)d_in[1];
    const float* bv = (const float*)d_in[2];
    float* out = (float*)d_out;

    const int nrows = out_size;          // 8388608 = 2^23
    const int block = 256;
    const int grid  = (nrows + block - 1) / block;  // 32768, exact fit

    sort3_linear_kernel<<<grid, block, 0, stream>>>(x, W, bv, out, nrows);
}